// Round 2
// baseline (16492.633 us; speedup 1.0000x reference)
//
#include <hip/hip_runtime.h>
#include <math.h>

#define BATCH 64
#define SEQ   512
#define HID   2048
#define NT    320          // 5 waves: 0-3 GEMM+update, 4 reducer
#define NBLK  256

typedef float f4 __attribute__((ext_vector_type(4)));

// ---- sc1 (coherence-point) accesses: write-through to L3 / read at L3 ----
__device__ __forceinline__ float gload(const float* p) {
    return __hip_atomic_load(p, __ATOMIC_RELAXED, __HIP_MEMORY_SCOPE_AGENT);
}
__device__ __forceinline__ void gstore(float* p, float v) {
    __hip_atomic_store(p, v, __ATOMIC_RELAXED, __HIP_MEMORY_SCOPE_AGENT);
}
__device__ __forceinline__ unsigned gloadu(const unsigned* p) {
    return __hip_atomic_load(p, __ATOMIC_RELAXED, __HIP_MEMORY_SCOPE_AGENT);
}
__device__ __forceinline__ void gstoreu(unsigned* p, unsigned v) {
    __hip_atomic_store(p, v, __ATOMIC_RELAXED, __HIP_MEMORY_SCOPE_AGENT);
}

// ---- fence-free grid barrier (equality-spin, monotonic; 0xAA-poison safe) --
__device__ __forceinline__ void gbar(unsigned t, unsigned* arrive,
                                     unsigned* epoch, int bid, int tid) {
    asm volatile("s_waitcnt vmcnt(0)" ::: "memory");  // all sc1 stores L3-acked
    __syncthreads();
    if (bid == 0) {
        if (tid > 0 && tid < NBLK) {
            while (gloadu(&arrive[tid]) != t) __builtin_amdgcn_s_sleep(1);
        }
        __syncthreads();
        if (tid == 0) gstoreu(epoch, t);
        __syncthreads();
    } else {
        if (tid == 0) {
            gstoreu(&arrive[bid], t);
            while (gloadu(epoch) != t) __builtin_amdgcn_s_sleep(1);
        }
        __syncthreads();
    }
}

// LDS: wsm[2048][8] W tile (64 KB) + redw[4][64][8] cross-wave partials (8 KB)
extern __shared__ float lds[];

__global__ void __launch_bounds__(NT, 1)
rnn_kernel(const float* __restrict__ x,      // [B,S]
           const float* __restrict__ noise,  // [B,S,H]
           const float* __restrict__ wi,     // [H]
           const float* __restrict__ wo,     // [H]
           const float* __restrict__ Av,     // [H]
           const float* __restrict__ rn,     // [H,H]
           const float* __restrict__ ovwi,
           const float* __restrict__ ovwo,
           const float* __restrict__ ovmn,
           const float* __restrict__ h0,     // [H]
           float* __restrict__ out,          // [B,S]
           float* __restrict__ ws)
{
    const int tid  = threadIdx.x;
    const int bid  = blockIdx.x;
    const int w    = tid >> 6;          // wave 0..4
    const int lane = tid & 63;
    // GEMM role (waves 0-3): lane = (bg, ks); lane owns 8 cols x 8 batches,
    // 8-way k-split across ks within the wave.
    const int ks = lane & 7;
    const int bg = lane >> 3;
    // update role (tid<256): column jU, batches b1/b2
    const int jU = tid & 7;
    const int b1 = tid >> 3;            // 0..31  (b1>>3 == w, wave-uniform)
    const int b2 = b1 + 32;
    // XCD-chunked column-block: 32 consecutive column-blocks per XCD so the
    // 4 blocks sharing a 128B noise/W line sit on one XCD's L2.
    const int cb = ((bid & 7) << 5) | (bid >> 3);
    const int jB = cb*8 + jU;

    float* wsm  = lds;                  // [2048][8]
    float* redw = lds + HID*8;          // [4][64][8] (bi-slot XOR-swizzled)

    // ws carve-up (floats): ~1.33 MB (identical to previous version)
    float* rg  = ws;                           // [2][HID][BATCH]  r, k-major
    float* ps  = rg + 2*HID*BATCH;             // [2][BATCH][NBLK] r.n partials
    float* po  = ps + 2*BATCH*NBLK;            // [2][BATCH][NBLK] r.wo partials
    float* sS  = po + 2*BATCH*NBLK;            // [64]
    float* red = sS + 64;                      // [NBLK][16] norm partials
    unsigned* flags      = (unsigned*)(red + NBLK*16);  // [8] reducer epochs
    unsigned* bar_arrive = flags + 8;                   // [NBLK]
    unsigned* bar_epoch  = bar_arrive + NBLK + 56;      // own line
    unsigned bt = 0;

    // ---- load W tile [2048][8] for this WG's columns (once, plain loads)
    {
        const f4* rn4 = (const f4*)rn;
        f4* wsm4 = (f4*)wsm;
        #pragma unroll
        for (int u = 0; u < 16; ++u) {
            if (tid < 256) {
                int idx = u*256 + tid;          // 0..4095 f4s
                int k = idx >> 1, half = idx & 1;
                wsm4[idx] = rn4[(size_t)k*512 + cb*2 + half];
            }
        }
    }

    // ---- norms: per-wave partials exchanged via global (all 5 waves help)
    float pwi = 0.f, pwo = 0.f;
    for (int i = tid; i < HID; i += NT) {
        float a = wi[i]; pwi = fmaf(a, a, pwi);
        float c = wo[i]; pwo = fmaf(c, c, pwo);
    }
    #pragma unroll
    for (int m = 32; m >= 1; m >>= 1) { pwi += __shfl_xor(pwi, m, 64); pwo += __shfl_xor(pwo, m, 64); }
    if (lane == 0) { gstore(&red[bid*16 + w], pwi); gstore(&red[bid*16 + 8 + w], pwo); }

    // ---- init: r_init = tanh(h0), store rg[0] + po[0] partials
    const float wiB = wi[jB], woB = wo[jB], aB = Av[jB];
    float h_1 = h0[jB];
    float h_2 = h_1;
    float r_1 = tanhf(h_1), r_2 = r_1;
    if (tid < 256) {
        gstore(&rg[jB*BATCH + b1], r_1);
        gstore(&rg[jB*BATCH + b2], r_2);
        float q1 = r_1*woB, q2 = r_2*woB;
        #pragma unroll
        for (int m = 4; m >= 1; m >>= 1) { q1 += __shfl_xor(q1, m, 8); q2 += __shfl_xor(q2, m, 8); }
        if (jU == 0) { gstore(&po[b1*NBLK + bid], q1); gstore(&po[b2*NBLK + bid], q2); }
    }
    gbar(++bt, bar_arrive, bar_epoch, bid, tid);

    float s_wi = 0.f, s_wo = 0.f;
    #pragma unroll
    for (int i2 = 0; i2 < 5; ++i2) { s_wi += gload(&red[bid*16 + i2]); s_wo += gload(&red[bid*16 + 8 + i2]); }
    const float hf = (float)HID, inv_hf = 1.0f/hf;
    const float c_mn = sqrtf(ovmn[0]*hf);
    const float nB = fmaf(ovwi[0]*hf/s_wi, wiB, c_mn*aB);  // n_rec[jB]
    const float mB = fmaf(ovwo[0]*hf/s_wo, woB, c_mn*aB);  // m_rec[jB]
    const float mi = mB*inv_hf;
    if (tid < 256) {
        float p1 = r_1*nB, p2 = r_2*nB;
        #pragma unroll
        for (int m = 4; m >= 1; m >>= 1) { p1 += __shfl_xor(p1, m, 8); p2 += __shfl_xor(p2, m, 8); }
        if (jU == 0) { gstore(&ps[b1*NBLK + bid], p1); gstore(&ps[b2*NBLK + bid], p2); }
    }
    gbar(++bt, bar_arrive, bar_epoch, bid, tid);

    // swizzled read offsets into redw for the update phase (constant per thread)
    const int rb1 = (b1 & ~7)*8 + (((b1 & 7) ^ (b1 >> 3)) & 7)*8 + jU;
    const int rb2 = (b2 & ~7)*8 + (((b2 & 7) ^ (b2 >> 3)) & 7)*8 + jU;

    for (int t = 0; t <= SEQ; ++t) {
        const int pr = t & 1, pw = pr ^ 1;
        const float* rgp = rg + (size_t)pr*(HID*BATCH);

        // Invalidate L1/L2 so the PLAIN loads below observe last step's sc1
        // (write-through) stores; L2 then serves the 32-block/XCD broadcast.
        __builtin_amdgcn_fence(__ATOMIC_ACQUIRE, "agent");

        // ---- reducer wave: sS/out from partials of r_{t-1} (|| with GEMM)
        if (w == 4 && bid < 8) {
            const int b   = bid*8 + (lane >> 3);
            const int sub = lane & 7;
            const float* psb = ps + (size_t)pr*(BATCH*NBLK) + b*NBLK;
            const float* pob = po + (size_t)pr*(BATCH*NBLK) + b*NBLK;
            float sb = 0.f, ob = 0.f;
            #pragma unroll
            for (int u = 0; u < 32; ++u) {
                sb += gload(psb + sub + u*8);
                ob += gload(pob + sub + u*8);
            }
            #pragma unroll
            for (int m = 4; m >= 1; m >>= 1) { sb += __shfl_xor(sb, m, 8); ob += __shfl_xor(ob, m, 8); }
            if (sub == 0) {
                gstore(&sS[b], sb);
                if (t > 0) out[(size_t)b*SEQ + (t-1)] = ob * inv_hf;
            }
            asm volatile("s_waitcnt vmcnt(0)" ::: "memory");   // sS visible first
            if (lane == 0) gstoreu(&flags[bid], (unsigned)(t+1));
        }
        if (t == SEQ) break;

        float x1 = 0.f, x2 = 0.f, nz1 = 0.f, nz2 = 0.f;
        if (w < 4) {
            // prefetch step inputs (used only in the update phase)
            x1 = x[b1*SEQ + t]; x2 = x[b2*SEQ + t];
            nz1 = noise[((size_t)b1*SEQ + t)*HID + jB];
            nz2 = noise[((size_t)b2*SEQ + t)*HID + jB];

            // ---- GEMM: direct-from-global r (L2-cached), W from LDS.
            // lane accumulates 8 cols x 8 batches over its 64 k-values.
            // Software-pipelined: 8 bodies of 8 k-iters, A/B register
            // double-buffer for the r loads so ~16 f4 loads stay in flight
            // across body boundaries (load latency hides under 1024cy of FMA).
            f4 acc0[8], acc1[8];
            #pragma unroll
            for (int c = 0; c < 8; ++c) {
                acc0[c] = (f4){0.f, 0.f, 0.f, 0.f};
                acc1[c] = (f4){0.f, 0.f, 0.f, 0.f};
            }
            const float* __restrict__ rb = rgp + (size_t)(w*512 + ks)*BATCH + bg*8;
            const float* __restrict__ wb = wsm + (w*512 + ks)*8;

            f4 bufA0[8], bufA1[8], bufB0[8], bufB1[8];
            // prologue: body 0 -> A
            #pragma unroll
            for (int u = 0; u < 8; ++u) {
                bufA0[u] = *(const f4*)(rb + (size_t)u*512);
                bufA1[u] = *(const f4*)(rb + (size_t)u*512 + 4);
            }
            #pragma unroll
            for (int h2 = 0; h2 < 4; ++h2) {
                const int iA = 2*h2;          // body consumed from A
                const int iB = 2*h2 + 1;      // body consumed from B
                const int iN = (iB + 1 > 7) ? 7 : (iB + 1);  // next->A (clamped)
                // issue loads for body iB into B (before A's FMAs)
                #pragma unroll
                for (int u = 0; u < 8; ++u) {
                    bufB0[u] = *(const f4*)(rb + (size_t)(iB*8 + u)*512);
                    bufB1[u] = *(const f4*)(rb + (size_t)(iB*8 + u)*512 + 4);
                }
                // FMA body iA from A
                #pragma unroll
                for (int u = 0; u < 8; ++u) {
                    const int i = iA*8 + u;
                    f4 wa0 = *(const f4*)(wb + i*64);         // cols 0..3
                    f4 wa1 = *(const f4*)(wb + i*64 + 4);     // cols 4..7
                    f4 ra0 = bufA0[u], ra1 = bufA1[u];
                    acc0[0] += ra0 * wa0.x; acc1[0] += ra1 * wa0.x;
                    acc0[1] += ra0 * wa0.y; acc1[1] += ra1 * wa0.y;
                    acc0[2] += ra0 * wa0.z; acc1[2] += ra1 * wa0.z;
                    acc0[3] += ra0 * wa0.w; acc1[3] += ra1 * wa0.w;
                    acc0[4] += ra0 * wa1.x; acc1[4] += ra1 * wa1.x;
                    acc0[5] += ra0 * wa1.y; acc1[5] += ra1 * wa1.y;
                    acc0[6] += ra0 * wa1.z; acc1[6] += ra1 * wa1.z;
                    acc0[7] += ra0 * wa1.w; acc1[7] += ra1 * wa1.w;
                }
                // issue loads for body iN into A (before B's FMAs)
                #pragma unroll
                for (int u = 0; u < 8; ++u) {
                    bufA0[u] = *(const f4*)(rb + (size_t)(iN*8 + u)*512);
                    bufA1[u] = *(const f4*)(rb + (size_t)(iN*8 + u)*512 + 4);
                }
                // FMA body iB from B
                #pragma unroll
                for (int u = 0; u < 8; ++u) {
                    const int i = iB*8 + u;
                    f4 wa0 = *(const f4*)(wb + i*64);
                    f4 wa1 = *(const f4*)(wb + i*64 + 4);
                    f4 ra0 = bufB0[u], ra1 = bufB1[u];
                    acc0[0] += ra0 * wa0.x; acc1[0] += ra1 * wa0.x;
                    acc0[1] += ra0 * wa0.y; acc1[1] += ra1 * wa0.y;
                    acc0[2] += ra0 * wa0.z; acc1[2] += ra1 * wa0.z;
                    acc0[3] += ra0 * wa0.w; acc1[3] += ra1 * wa0.w;
                    acc0[4] += ra0 * wa1.x; acc1[4] += ra1 * wa1.x;
                    acc0[5] += ra0 * wa1.y; acc1[5] += ra1 * wa1.y;
                    acc0[6] += ra0 * wa1.z; acc1[6] += ra1 * wa1.z;
                    acc0[7] += ra0 * wa1.w; acc1[7] += ra1 * wa1.w;
                }
            }
            // reduce over the 8-way in-wave k-split (ks = lane&7)
            #pragma unroll
            for (int m = 1; m <= 4; m <<= 1) {
                #pragma unroll
                for (int c = 0; c < 8; ++c) {
                    #pragma unroll
                    for (int q = 0; q < 4; ++q) {
                        acc0[c][q] += __shfl_xor(acc0[c][q], m, 64);
                        acc1[c][q] += __shfl_xor(acc1[c][q], m, 64);
                    }
                }
            }
            if (ks == 0) {
                // redw[w][b][c], bi-slot XOR-swizzled by bg to spread banks
                float* dst = redw + w*512 + bg*64;
                #pragma unroll
                for (int bi = 0; bi < 4; ++bi) {
                    int slot = (bi ^ bg) & 7;
                    *(f4*)(dst + slot*8)     = (f4){acc0[0][bi], acc0[1][bi], acc0[2][bi], acc0[3][bi]};
                    *(f4*)(dst + slot*8 + 4) = (f4){acc0[4][bi], acc0[5][bi], acc0[6][bi], acc0[7][bi]};
                }
                #pragma unroll
                for (int bi = 0; bi < 4; ++bi) {
                    int slot = ((bi + 4) ^ bg) & 7;
                    *(f4*)(dst + slot*8)     = (f4){acc1[0][bi], acc1[1][bi], acc1[2][bi], acc1[3][bi]};
                    *(f4*)(dst + slot*8 + 4) = (f4){acc1[4][bi], acc1[5][bi], acc1[6][bi], acc1[7][bi]};
                }
            }
        }
        __syncthreads();

        // ---- in-WG h/r update (tid<256)
        if (tid < 256) {
            float accA = redw[rb1] + redw[512 + rb1] + redw[1024 + rb1] + redw[1536 + rb1];
            float accB = redw[rb2] + redw[512 + rb2] + redw[1024 + rb2] + redw[1536 + rb2];
            // wait for reducer's sS of this step (wave-uniform flags: b1>>3==w)
            const unsigned want = (unsigned)(t + 1);
            while (gloadu(&flags[b1 >> 3]) != want) __builtin_amdgcn_s_sleep(1);
            while (gloadu(&flags[b2 >> 3]) != want) __builtin_amdgcn_s_sleep(1);
            float sb1 = gload(&sS[b1]);
            float sb2 = gload(&sS[b2]);

            float g1 = accA + sb1*mi + x1*wiB;
            float g2 = accB + sb2*mi + x2*wiB;
            h_1 += 0.05f*nz1 + 0.2f*(g1 - h_1);
            h_2 += 0.05f*nz2 + 0.2f*(g2 - h_2);
            r_1 = tanhf(h_1); r_2 = tanhf(h_2);
            float* rgw = rg + (size_t)pw*(HID*BATCH);
            gstore(&rgw[jB*BATCH + b1], r_1);
            gstore(&rgw[jB*BATCH + b2], r_2);
            float p1 = r_1*nB, p2 = r_2*nB, q1 = r_1*woB, q2 = r_2*woB;
            #pragma unroll
            for (int m = 4; m >= 1; m >>= 1) {
                p1 += __shfl_xor(p1, m, 8); p2 += __shfl_xor(p2, m, 8);
                q1 += __shfl_xor(q1, m, 8); q2 += __shfl_xor(q2, m, 8);
            }
            if (jU == 0) {
                float* psw = ps + (size_t)pw*(BATCH*NBLK);
                float* pow_ = po + (size_t)pw*(BATCH*NBLK);
                gstore(&psw[b1*NBLK + bid], p1); gstore(&psw[b2*NBLK + bid], p2);
                gstore(&pow_[b1*NBLK + bid], q1); gstore(&pow_[b2*NBLK + bid], q2);
            }
        }
        gbar(++bt, bar_arrive, bar_epoch, bid, tid);   // ONE barrier per step
    }
}

extern "C" void kernel_launch(void* const* d_in, const int* in_sizes, int n_in,
                              void* d_out, int out_size, void* d_ws, size_t ws_size,
                              hipStream_t stream) {
    const float* x     = (const float*)d_in[0];
    const float* noise = (const float*)d_in[1];
    const float* wi    = (const float*)d_in[2];
    const float* wo    = (const float*)d_in[3];
    const float* Av    = (const float*)d_in[4];
    const float* rn    = (const float*)d_in[5];
    const float* ovwi  = (const float*)d_in[6];
    const float* ovwo  = (const float*)d_in[7];
    const float* ovmn  = (const float*)d_in[8];
    const float* h0    = (const float*)d_in[9];
    float* out = (float*)d_out;
    float* ws  = (float*)d_ws;   // needs ~1.4 MB

    (void)hipFuncSetAttribute((const void*)rnn_kernel,
                              hipFuncAttributeMaxDynamicSharedMemorySize, 73728);

    void* args[] = { &x, &noise, &wi, &wo, &Av, &rn, &ovwi, &ovwo, &ovmn, &h0, &out, &ws };
    hipLaunchCooperativeKernel((void*)rnn_kernel, dim3(NBLK), dim3(NT),
                               args, 73728, stream);
}

// Round 4
// 14510.641 us; speedup vs baseline: 1.1366x; 1.1366x over previous
//
#include <hip/hip_runtime.h>
#include <math.h>

#define BATCH 64
#define SEQ   512
#define HID   2048
#define NT    320          // 5 waves: 0-3 GEMM+update, 4 out-reducer (off-path)
#define NBLK  256

typedef float f4 __attribute__((ext_vector_type(4)));

// ---- sc1 (coherence-point) accesses: write-through to L3 / read at L3 ----
__device__ __forceinline__ float gload(const float* p) {
    return __hip_atomic_load(p, __ATOMIC_RELAXED, __HIP_MEMORY_SCOPE_AGENT);
}
__device__ __forceinline__ void gstore(float* p, float v) {
    __hip_atomic_store(p, v, __ATOMIC_RELAXED, __HIP_MEMORY_SCOPE_AGENT);
}
__device__ __forceinline__ unsigned gloadu(const unsigned* p) {
    return __hip_atomic_load(p, __ATOMIC_RELAXED, __HIP_MEMORY_SCOPE_AGENT);
}
__device__ __forceinline__ void gstoreu(unsigned* p, unsigned v) {
    __hip_atomic_store(p, v, __ATOMIC_RELAXED, __HIP_MEMORY_SCOPE_AGENT);
}

// ---- fence-free grid barrier (equality-spin, monotonic; 0xAA-poison safe) --
__device__ __forceinline__ void gbar(unsigned t, unsigned* arrive,
                                     unsigned* epoch, int bid, int tid) {
    asm volatile("s_waitcnt vmcnt(0)" ::: "memory");  // all sc1 stores L3-acked
    __syncthreads();
    if (bid == 0) {
        if (tid > 0 && tid < NBLK) {
            while (gloadu(&arrive[tid]) != t) __builtin_amdgcn_s_sleep(1);
        }
        __syncthreads();
        if (tid == 0) gstoreu(epoch, t);
        __syncthreads();
    } else {
        if (tid == 0) {
            gstoreu(&arrive[bid], t);
            while (gloadu(epoch) != t) __builtin_amdgcn_s_sleep(1);
        }
        __syncthreads();
    }
}

// LDS: wsm[2048][8] W tile (64 KB) + redw[4][64][8] (8 KB) + nsm[2048] (8 KB)
//      + redS[4][64] (1 KB)  => 82944 B
extern __shared__ float lds[];

__global__ void __launch_bounds__(NT, 1)
rnn_kernel(const float* __restrict__ x,      // [B,S]
           const float* __restrict__ noise,  // [B,S,H]
           const float* __restrict__ wi,     // [H]
           const float* __restrict__ wo,     // [H]
           const float* __restrict__ Av,     // [H]
           const float* __restrict__ rn,     // [H,H]
           const float* __restrict__ ovwi,
           const float* __restrict__ ovwo,
           const float* __restrict__ ovmn,
           const float* __restrict__ h0,     // [H]
           float* __restrict__ out,          // [B,S]
           float* __restrict__ ws)
{
    const int tid  = threadIdx.x;
    const int bid  = blockIdx.x;
    const int w    = tid >> 6;          // wave 0..4
    const int lane = tid & 63;
    // GEMM role (waves 0-3): lane = (bg, ks); lane owns 8 cols x 8 batches,
    // 8-way k-split across ks within the wave.
    const int ks = lane & 7;
    const int bg = lane >> 3;
    // update role (tid<256): column jU, batches b1/b2
    const int jU = tid & 7;
    const int b1 = tid >> 3;            // 0..31
    const int b2 = b1 + 32;
    // XCD-chunked column-block swizzle for L2 locality
    const int cb = ((bid & 7) << 5) | (bid >> 3);
    const int jB = cb*8 + jU;

    float* wsm  = lds;                  // [2048][8]
    float* redw = lds + HID*8;          // [4][64][8] (bi-slot XOR-swizzled)
    float* nsm  = redw + 2048;          // [2048] n_rec vector
    float* redS = nsm + HID;            // [4][64] per-wave r.n partials

    // ws carve-up (floats): ~1.2 MB
    float* rg  = ws;                           // [2][HID][BATCH]  r, k-major
    float* po  = rg + 2*HID*BATCH;             // [2][BATCH][NBLK] r.wo partials
    float* red = po + 2*BATCH*NBLK;            // [NBLK][16] norm partials
    unsigned* bar_arrive = (unsigned*)(red + NBLK*16);  // [NBLK]
    unsigned* bar_epoch  = bar_arrive + NBLK + 56;      // own line
    unsigned bt = 0;

    // ---- load W tile [2048][8] for this WG's columns (once, plain loads)
    {
        const f4* rn4 = (const f4*)rn;
        f4* wsm4 = (f4*)wsm;
        #pragma unroll
        for (int u = 0; u < 16; ++u) {
            if (tid < 256) {
                int idx = u*256 + tid;          // 0..4095 f4s
                int k = idx >> 1, half = idx & 1;
                wsm4[idx] = rn4[(size_t)k*512 + cb*2 + half];
            }
        }
    }

    // ---- norms: per-wave partials exchanged via global (all 5 waves help)
    float pwi = 0.f, pwo = 0.f;
    for (int i = tid; i < HID; i += NT) {
        float a = wi[i]; pwi = fmaf(a, a, pwi);
        float c = wo[i]; pwo = fmaf(c, c, pwo);
    }
    #pragma unroll
    for (int m = 32; m >= 1; m >>= 1) { pwi += __shfl_xor(pwi, m, 64); pwo += __shfl_xor(pwo, m, 64); }
    if (lane == 0) { gstore(&red[bid*16 + w], pwi); gstore(&red[bid*16 + 8 + w], pwo); }

    // ---- init: r_init = tanh(h0), store rg[0] + po[0] partials
    const float wiB = wi[jB], woB = wo[jB], aB = Av[jB];
    float h_1 = h0[jB];
    float h_2 = h_1;
    float r_1 = tanhf(h_1), r_2 = r_1;
    if (tid < 256) {
        gstore(&rg[jB*BATCH + b1], r_1);
        gstore(&rg[jB*BATCH + b2], r_2);
        float q1 = r_1*woB, q2 = r_2*woB;
        #pragma unroll
        for (int m = 4; m >= 1; m >>= 1) { q1 += __shfl_xor(q1, m, 8); q2 += __shfl_xor(q2, m, 8); }
        if (jU == 0) { gstore(&po[b1*NBLK + bid], q1); gstore(&po[b2*NBLK + bid], q2); }
    }
    gbar(++bt, bar_arrive, bar_epoch, bid, tid);

    float s_wi = 0.f, s_wo = 0.f;
    #pragma unroll
    for (int i2 = 0; i2 < 5; ++i2) { s_wi += gload(&red[bid*16 + i2]); s_wo += gload(&red[bid*16 + 8 + i2]); }
    const float hf = (float)HID, inv_hf = 1.0f/hf;
    const float c_mn = sqrtf(ovmn[0]*hf);
    const float cwi  = ovwi[0]*hf/s_wi;
    const float mB = fmaf(ovwo[0]*hf/s_wo, woB, c_mn*aB);  // m_rec[jB]
    const float mi = mB*inv_hf;
    // ---- stage the full n_rec vector in LDS (enables in-block rank-1 sum)
    for (int k = tid; k < HID; k += NT) {
        nsm[k] = fmaf(cwi, wi[k], c_mn*Av[k]);
    }
    gbar(++bt, bar_arrive, bar_epoch, bid, tid);   // syncthreads makes nsm visible

    // swizzled read offsets into redw for the update phase (constant per thread)
    const int rb1 = (b1 & ~7)*8 + (((b1 & 7) ^ (b1 >> 3)) & 7)*8 + jU;
    const int rb2 = (b2 & ~7)*8 + (((b2 & 7) ^ (b2 >> 3)) & 7)*8 + jU;

    for (int t = 0; t <= SEQ; ++t) {
        const int pr = t & 1, pw = pr ^ 1;
        const float* rgp = rg + (size_t)pr*(HID*BATCH);

        // prefetch read-only step inputs before the invalidate (in-flight loads
        // complete with data; no coherence requirement on x/noise)
        float x1 = 0.f, x2 = 0.f, nz1 = 0.f, nz2 = 0.f;
        if (t < SEQ && w < 4) {
            x1 = x[b1*SEQ + t]; x2 = x[b2*SEQ + t];
            nz1 = noise[((size_t)b1*SEQ + t)*HID + jB];
            nz2 = noise[((size_t)b2*SEQ + t)*HID + jB];
        }

        // Invalidate L1/L2 so the PLAIN loads below observe last step's sc1
        // (write-through) stores; L2 then serves the 32-block/XCD broadcast.
        __builtin_amdgcn_fence(__ATOMIC_ACQUIRE, "agent");

        // ---- out-reducer wave: out[t-1] from po partials of r_{t-1}.
        // Fully OFF the critical path now (nothing waits on it within the
        // step; its loads finish before this step's gbar, and po[pr] is only
        // rewritten after that gbar -> WAR-safe).
        if (w == 4 && bid < 8) {
            const int b   = bid*8 + (lane >> 3);
            const int sub = lane & 7;
            const float* pob = po + (size_t)pr*(BATCH*NBLK) + b*NBLK;
            float ob = 0.f;
            #pragma unroll
            for (int u = 0; u < 32; ++u) ob += gload(pob + sub + u*8);
            #pragma unroll
            for (int m = 4; m >= 1; m >>= 1) ob += __shfl_xor(ob, m, 8);
            if (sub == 0 && t > 0) out[(size_t)b*SEQ + (t-1)] = ob * inv_hf;
        }
        if (t == SEQ) break;

        if (w < 4) {
            // ---- GEMM: direct-from-global r (L2-cached), W from LDS.
            // lane accumulates 8 cols x 8 batches over its 64 k-values,
            // PLUS the local rank-1 partial S[b] = sum_k r[k,b]*n[k].
            f4 acc0[8], acc1[8];
            #pragma unroll
            for (int c = 0; c < 8; ++c) {
                acc0[c] = (f4){0.f, 0.f, 0.f, 0.f};
                acc1[c] = (f4){0.f, 0.f, 0.f, 0.f};
            }
            f4 sv0 = (f4){0.f, 0.f, 0.f, 0.f};
            f4 sv1 = (f4){0.f, 0.f, 0.f, 0.f};
            const float* __restrict__ rb = rgp + (size_t)(w*512 + ks)*BATCH + bg*8;
            const float* __restrict__ wb = wsm + (w*512 + ks)*8;
            const float* __restrict__ nsb = nsm + w*512 + ks;
            #pragma unroll 4
            for (int i = 0; i < 64; ++i) {
                f4 ra0 = *(const f4*)(rb + i*512);        // batches bg*8+0..3
                f4 ra1 = *(const f4*)(rb + i*512 + 4);    // batches bg*8+4..7
                f4 wa0 = *(const f4*)(wb + i*64);         // cols 0..3
                f4 wa1 = *(const f4*)(wb + i*64 + 4);     // cols 4..7
                float nk = nsb[i*8];                      // n_rec[k]
                acc0[0] += ra0 * wa0.x; acc1[0] += ra1 * wa0.x;
                acc0[1] += ra0 * wa0.y; acc1[1] += ra1 * wa0.y;
                acc0[2] += ra0 * wa0.z; acc1[2] += ra1 * wa0.z;
                acc0[3] += ra0 * wa0.w; acc1[3] += ra1 * wa0.w;
                acc0[4] += ra0 * wa1.x; acc1[4] += ra1 * wa1.x;
                acc0[5] += ra0 * wa1.y; acc1[5] += ra1 * wa1.y;
                acc0[6] += ra0 * wa1.z; acc1[6] += ra1 * wa1.z;
                acc0[7] += ra0 * wa1.w; acc1[7] += ra1 * wa1.w;
                sv0 += ra0 * nk; sv1 += ra1 * nk;
            }
            // reduce over the 8-way in-wave k-split (ks = lane&7)
            #pragma unroll
            for (int m = 1; m <= 4; m <<= 1) {
                #pragma unroll
                for (int c = 0; c < 8; ++c) {
                    #pragma unroll
                    for (int q = 0; q < 4; ++q) {
                        acc0[c][q] += __shfl_xor(acc0[c][q], m, 64);
                        acc1[c][q] += __shfl_xor(acc1[c][q], m, 64);
                    }
                }
                #pragma unroll
                for (int q = 0; q < 4; ++q) {
                    sv0[q] += __shfl_xor(sv0[q], m, 64);
                    sv1[q] += __shfl_xor(sv1[q], m, 64);
                }
            }
            if (ks == 0) {
                // redw[w][b][c], bi-slot XOR-swizzled by bg to spread banks
                float* dst = redw + w*512 + bg*64;
                #pragma unroll
                for (int bi = 0; bi < 4; ++bi) {
                    int slot = (bi ^ bg) & 7;
                    *(f4*)(dst + slot*8)     = (f4){acc0[0][bi], acc0[1][bi], acc0[2][bi], acc0[3][bi]};
                    *(f4*)(dst + slot*8 + 4) = (f4){acc0[4][bi], acc0[5][bi], acc0[6][bi], acc0[7][bi]};
                }
                #pragma unroll
                for (int bi = 0; bi < 4; ++bi) {
                    int slot = ((bi + 4) ^ bg) & 7;
                    *(f4*)(dst + slot*8)     = (f4){acc1[0][bi], acc1[1][bi], acc1[2][bi], acc1[3][bi]};
                    *(f4*)(dst + slot*8 + 4) = (f4){acc1[4][bi], acc1[5][bi], acc1[6][bi], acc1[7][bi]};
                }
                // local rank-1 partials: redS[w][bg*8 + 0..7]
                *(f4*)(redS + w*64 + bg*8)     = sv0;
                *(f4*)(redS + w*64 + bg*8 + 4) = sv1;
            }
        }
        __syncthreads();

        // ---- in-WG h/r update (tid<256): NO global spin, NO global loads.
        if (tid < 256) {
            float accA = redw[rb1] + redw[512 + rb1] + redw[1024 + rb1] + redw[1536 + rb1];
            float accB = redw[rb2] + redw[512 + rb2] + redw[1024 + rb2] + redw[1536 + rb2];
            float sA = redS[b1] + redS[64 + b1] + redS[128 + b1] + redS[192 + b1];
            float sB = redS[b2] + redS[64 + b2] + redS[128 + b2] + redS[192 + b2];

            float g1 = accA + sA*mi + x1*wiB;
            float g2 = accB + sB*mi + x2*wiB;
            h_1 += 0.05f*nz1 + 0.2f*(g1 - h_1);
            h_2 += 0.05f*nz2 + 0.2f*(g2 - h_2);
            r_1 = tanhf(h_1); r_2 = tanhf(h_2);
            float* rgw = rg + (size_t)pw*(HID*BATCH);
            gstore(&rgw[jB*BATCH + b1], r_1);
            gstore(&rgw[jB*BATCH + b2], r_2);
            float q1 = r_1*woB, q2 = r_2*woB;
            #pragma unroll
            for (int m = 4; m >= 1; m >>= 1) {
                q1 += __shfl_xor(q1, m, 8); q2 += __shfl_xor(q2, m, 8);
            }
            if (jU == 0) {
                float* pow_ = po + (size_t)pw*(BATCH*NBLK);
                gstore(&pow_[b1*NBLK + bid], q1); gstore(&pow_[b2*NBLK + bid], q2);
            }
        }
        gbar(++bt, bar_arrive, bar_epoch, bid, tid);   // ONE barrier per step
    }
}

extern "C" void kernel_launch(void* const* d_in, const int* in_sizes, int n_in,
                              void* d_out, int out_size, void* d_ws, size_t ws_size,
                              hipStream_t stream) {
    const float* x     = (const float*)d_in[0];
    const float* noise = (const float*)d_in[1];
    const float* wi    = (const float*)d_in[2];
    const float* wo    = (const float*)d_in[3];
    const float* Av    = (const float*)d_in[4];
    const float* rn    = (const float*)d_in[5];
    const float* ovwi  = (const float*)d_in[6];
    const float* ovwo  = (const float*)d_in[7];
    const float* ovmn  = (const float*)d_in[8];
    const float* h0    = (const float*)d_in[9];
    float* out = (float*)d_out;
    float* ws  = (float*)d_ws;   // needs ~1.2 MB

    (void)hipFuncSetAttribute((const void*)rnn_kernel,
                              hipFuncAttributeMaxDynamicSharedMemorySize, 82944);

    void* args[] = { &x, &noise, &wi, &wo, &Av, &rn, &ovwi, &ovwo, &ovmn, &h0, &out, &ws };
    hipLaunchCooperativeKernel((void*)rnn_kernel, dim3(NBLK), dim3(NT),
                               args, 82944, stream);
}